// Round 6
// baseline (286.744 us; speedup 1.0000x reference)
//
#include <hip/hip_runtime.h>
#include <math.h>

#define BATCH 2
#define SEQ   2048
#define CDIM  1024
#define NHEAD 16
#define HDIM  64
#define TOKS  (BATCH * SEQ)   // 4096

typedef __bf16 bf16x8 __attribute__((ext_vector_type(8)));
typedef __bf16 bf16x2 __attribute__((ext_vector_type(2)));
typedef float  f32x4  __attribute__((ext_vector_type(4)));
typedef float  f32x16 __attribute__((ext_vector_type(16)));

#define MFMA16(a, b, c) __builtin_amdgcn_mfma_f32_16x16x32_bf16(a, b, c, 0, 0, 0)
#define MFMA32(a, b, c) __builtin_amdgcn_mfma_f32_32x32x16_bf16(a, b, c, 0, 0, 0)

// 0.125 * log2(e): folded into Q projection so p = exp2(s) == softmax-exact
#define QSCALE 0.1803368801111204f

__device__ __forceinline__ void gload_lds16(const __bf16* g, __bf16* l) {
    __builtin_amdgcn_global_load_lds(
        (const __attribute__((address_space(1))) unsigned int*)g,
        (__attribute__((address_space(3))) unsigned int*)l, 16, 0, 0);
}

// ---------------------------------------------------------------------------
// Prep: blocks [0,6144): fp32->bf16 convert of q,k,v (2048 blocks each).
//       blocks [6144,7168): W (KxN fp32) -> Wt (NxK bf16) transpose, 4 mats.
// ---------------------------------------------------------------------------
__global__ __launch_bounds__(256) void prep_kernel(
    const float* __restrict__ q, const float* __restrict__ k, const float* __restrict__ v,
    __bf16* __restrict__ qo, __bf16* __restrict__ ko, __bf16* __restrict__ vo,
    const float* __restrict__ W0, const float* __restrict__ W1,
    const float* __restrict__ W2, const float* __restrict__ W3,
    __bf16* __restrict__ T0, __bf16* __restrict__ T1,
    __bf16* __restrict__ T2, __bf16* __restrict__ T3)
{
    __shared__ __bf16 Ts[64][72];
    const int bx = blockIdx.x;
    const int tid = threadIdx.x;

    if (bx < 6144) {
        const int t = bx >> 11;
        const size_t i = ((size_t)(bx & 2047) * 256 + tid) * 8;
        const float* s = t == 0 ? q : (t == 1 ? k : v);
        __bf16* d = t == 0 ? qo : (t == 1 ? ko : vo);
        const float4 x = *(const float4*)&s[i];
        const float4 y = *(const float4*)&s[i + 4];
        bf16x8 o;
        o[0] = (__bf16)x.x; o[1] = (__bf16)x.y; o[2] = (__bf16)x.z; o[3] = (__bf16)x.w;
        o[4] = (__bf16)y.x; o[5] = (__bf16)y.y; o[6] = (__bf16)y.z; o[7] = (__bf16)y.w;
        *(bf16x8*)&d[i] = o;
        return;
    }

    const int t  = bx - 6144;
    const int z  = t >> 8;
    const int ry = (t & 255) >> 4;
    const int rx = t & 15;
    const float* W = z == 0 ? W0 : z == 1 ? W1 : z == 2 ? W2 : W3;
    __bf16* T = z == 0 ? T0 : z == 1 ? T1 : z == 2 ? T2 : T3;
    const int rb = ry * 64, cb = rx * 64;
    const int r = tid >> 4;
    const int c4 = (tid & 15) * 4;
#pragma unroll
    for (int p = 0; p < 4; p++) {
        const int rr = p * 16 + r;
        const float4 w4 = *(const float4*)&W[(size_t)(rb + rr) * CDIM + cb + c4];
        Ts[c4 + 0][rr] = (__bf16)w4.x;
        Ts[c4 + 1][rr] = (__bf16)w4.y;
        Ts[c4 + 2][rr] = (__bf16)w4.z;
        Ts[c4 + 3][rr] = (__bf16)w4.w;
    }
    __syncthreads();
    const int n = tid >> 2;
    const int k16 = (tid & 3) * 16;
    *(bf16x8*)&T[(size_t)(cb + n) * CDIM + rb + k16]     = *(const bf16x8*)&Ts[n][k16];
    *(bf16x8*)&T[(size_t)(cb + n) * CDIM + rb + k16 + 8] = *(const bf16x8*)&Ts[n][k16 + 8];
}

// ---------------------------------------------------------------------------
// Fused QKV projection GEMM, one dispatch, z selects:
//   z=0: Qh = (q@Wq + bq)*QSCALE  -> (B,H,L,D) bf16
//   z=1: Kh = (k@Wk + bk)         -> (B,H,L,D) bf16
//   z=2: Vht = (Wv^T @ v^T + bv)  -> [chan][tok] bf16, NATURAL token order
//
// 512 threads / 8 waves on the 128x128 tile (wave grid 4x2, 32x64 out per
// wave, acc[2][4]) -> 3 blocks/CU x 8 waves = 24 waves/CU.
// Chunked bijective XCD swizzle (768 blocks, 96/XCD).
// ---------------------------------------------------------------------------
__global__ __launch_bounds__(512, 6) void qkv_gemm_kernel(
    const __bf16* __restrict__ qb, const __bf16* __restrict__ kb,
    const __bf16* __restrict__ vb,
    const __bf16* __restrict__ Wqt, const __bf16* __restrict__ Wkt,
    const __bf16* __restrict__ Wvt,
    const float* __restrict__ bq, const float* __restrict__ bk,
    const float* __restrict__ bv,
    __bf16* __restrict__ Qh, __bf16* __restrict__ Kh, __bf16* __restrict__ Vht)
{
    __shared__ __bf16 As[128 * 32];
    __shared__ __bf16 Bs[128 * 32];

    // chunked XCD swizzle: 768 blocks, 96 consecutive per XCD (768 % 8 == 0)
    const int lin = blockIdx.x + (blockIdx.y << 3) + (blockIdx.z << 8);
    const int nl  = (lin & 7) * 96 + (lin >> 3);
    const int bx  = nl & 7;
    const int by  = (nl >> 3) & 31;
    const int z   = nl >> 8;

    const __bf16* A    = z == 0 ? qb : z == 1 ? kb : Wvt;
    const __bf16* Bt   = z == 0 ? Wqt : z == 1 ? Wkt : vb;
    const float*  bias = z == 0 ? bq : z == 1 ? bk : bv;

    const int tid  = threadIdx.x;
    const int w    = tid >> 6;     // 0..7
    const int lane = tid & 63;
    const int quad = lane >> 4;
    const int c    = lane & 15;
    const int wm   = w >> 1;       // 0..3: 32-row strip
    const int wn   = w & 1;        // 0..1: 64-col strip
    const int rowBase = (z == 2 ? bx : by) * 128;
    const int colBase = (z == 2 ? by : bx) * 128;

    const int sr = lane >> 2;        // 0..15 staging row within wave's strip
    const int sk = (lane & 3) * 8;   // staging k-offset (elements)

    f32x4 acc[2][4];
#pragma unroll
    for (int i = 0; i < 2; i++)
#pragma unroll
        for (int j = 0; j < 4; j++) acc[i][j] = (f32x4){0, 0, 0, 0};

    const __bf16* srcA = A  + (size_t)(rowBase + w * 16 + sr) * CDIM + sk;
    const __bf16* srcB = Bt + (size_t)(colBase + w * 16 + sr) * CDIM + sk;
    __bf16* dstA = &As[w * 16 * 32];
    __bf16* dstB = &Bs[w * 16 * 32];

    for (int k0 = 0; k0 < CDIM; k0 += 32) {
        gload_lds16(srcA + k0, dstA);
        gload_lds16(srcB + k0, dstB);
        __syncthreads();

        bf16x8 af[2], bf[4];
#pragma unroll
        for (int i = 0; i < 2; i++)
            af[i] = *(const bf16x8*)&As[(wm * 32 + i * 16 + c) * 32 + quad * 8];
#pragma unroll
        for (int i = 0; i < 4; i++)
            bf[i] = *(const bf16x8*)&Bs[(wn * 64 + i * 16 + c) * 32 + quad * 8];
#pragma unroll
        for (int mi = 0; mi < 2; mi++)
#pragma unroll
            for (int ni = 0; ni < 4; ni++)
                acc[mi][ni] = MFMA16(af[mi], bf[ni], acc[mi][ni]);
        __syncthreads();
    }

#pragma unroll
    for (int mi = 0; mi < 2; mi++) {
#pragma unroll
        for (int ni = 0; ni < 4; ni++) {
            const int col = colBase + wn * 64 + ni * 16 + c;
#pragma unroll
            for (int r = 0; r < 4; r++) {
                const int row = rowBase + wm * 32 + mi * 16 + quad * 4 + r;
                const float val = acc[mi][ni][r];
                if (z == 2) {
                    // natural token order (attn consumes keys in order)
                    Vht[(size_t)row * TOKS + col] = (__bf16)(val + bias[row]);
                } else {
                    const int b = row >> 11, l = row & 2047;
                    const int h = col >> 6,  d = col & 63;
                    const float s = (z == 0) ? QSCALE : 1.0f;
                    __bf16* outp = (z == 0) ? Qh : Kh;
                    outp[((((size_t)b * NHEAD + h) * SEQ) + l) * HDIM + d] =
                        (__bf16)((val + bias[col]) * s);
                }
            }
        }
    }
}

// ---------------------------------------------------------------------------
// Final projection GEMM: out(fp32) = Yb(bf16) @ Wot^T + bo.
// 512 threads / 8 waves on the 128x64 tile; chunked XCD swizzle.
// ---------------------------------------------------------------------------
__global__ __launch_bounds__(512, 4) void out_gemm_kernel(
    const __bf16* __restrict__ A, const __bf16* __restrict__ Bt,
    const float* __restrict__ bias, float* __restrict__ out)
{
    __shared__ __bf16 As[128 * 32];
    __shared__ __bf16 Bs[64 * 32];

    const int lin = blockIdx.x + (blockIdx.y << 4);
    const int nl  = (lin & 7) * 64 + (lin >> 3);
    const int bx  = nl & 15;
    const int by  = nl >> 4;

    const int tid  = threadIdx.x;
    const int w    = tid >> 6;     // 0..7
    const int lane = tid & 63;
    const int quad = lane >> 4;
    const int c    = lane & 15;
    const int wm   = w >> 1;       // 0..3: 32-row strip
    const int wn   = w & 1;        // 0..1: 32-col strip
    const int rowBase = by * 128;
    const int colBase = bx * 64;
    const int sr = lane >> 2;
    const int sk = (lane & 3) * 8;

    f32x4 acc[2][2];
#pragma unroll
    for (int i = 0; i < 2; i++)
#pragma unroll
        for (int j = 0; j < 2; j++) acc[i][j] = (f32x4){0, 0, 0, 0};

    const __bf16* srcA = A + (size_t)(rowBase + w * 16 + sr) * CDIM + sk;
    const __bf16* srcB = Bt + (size_t)(colBase + (w & 3) * 16 + sr) * CDIM + sk;
    __bf16* dstA = &As[w * 16 * 32];
    __bf16* dstB = &Bs[(w & 3) * 16 * 32];

    for (int k0 = 0; k0 < CDIM; k0 += 32) {
        gload_lds16(srcA + k0, dstA);
        if (w < 4) gload_lds16(srcB + k0, dstB);
        __syncthreads();

        bf16x8 af[2], bf[2];
#pragma unroll
        for (int i = 0; i < 2; i++)
            af[i] = *(const bf16x8*)&As[(wm * 32 + i * 16 + c) * 32 + quad * 8];
#pragma unroll
        for (int i = 0; i < 2; i++)
            bf[i] = *(const bf16x8*)&Bs[(wn * 32 + i * 16 + c) * 32 + quad * 8];
#pragma unroll
        for (int mi = 0; mi < 2; mi++)
#pragma unroll
            for (int ni = 0; ni < 2; ni++)
                acc[mi][ni] = MFMA16(af[mi], bf[ni], acc[mi][ni]);
        __syncthreads();
    }

#pragma unroll
    for (int mi = 0; mi < 2; mi++) {
#pragma unroll
        for (int ni = 0; ni < 2; ni++) {
            const int col = colBase + wn * 32 + ni * 16 + c;
#pragma unroll
            for (int r = 0; r < 4; r++) {
                const int row = rowBase + wm * 32 + mi * 16 + quad * 4 + r;
                out[(size_t)row * CDIM + col] = acc[mi][ni][r] + bias[col];
            }
        }
    }
}

// ---------------------------------------------------------------------------
// Attention v9: LDS-free. 256 thr / 4 waves, 32 q-rows/wave via 32x32x16
// MFMA, swapped QK^T (S^T = mfma(K,Q)), P in registers (v8 softmax path).
// K/V fragments load DIRECTLY global->registers: the 16 KB per-tile K/V
// working set is L1-resident (32 KB/CU) and L2 holds the head-pinned 2 MB
// per-XCD set, so LDS staging + per-tile barriers were pure overhead
// (8 waves x 16 b128 re-reads/tile ~50% LDS busy + barrier drains).
// ZERO barriers in the main loop; compiler's per-use vmcnt gives the
// never-drain pipeline: V(t) issued at tile top (consumed after QK+exp2),
// K(t+1) issued into the other ping-pong buffer (consumed next tile).
// Named reg arrays KA/KB (no runtime indexing -> no scratch).
// ---------------------------------------------------------------------------
__device__ __forceinline__ void attn_load_k(const __bf16* kp, bf16x8 (&K)[8]) {
#pragma unroll
    for (int kt = 0; kt < 2; kt++)
#pragma unroll
        for (int ks = 0; ks < 4; ks++)
            K[kt * 4 + ks] = *(const bf16x8*)(kp + (size_t)kt * 32 * HDIM + ks * 16);
}

__device__ __forceinline__ void attn_load_v(const __bf16* vp, bf16x8 (&V)[8]) {
#pragma unroll
    for (int dt = 0; dt < 2; dt++)
#pragma unroll
        for (int kt = 0; kt < 2; kt++)
#pragma unroll
            for (int kl = 0; kl < 2; kl++)
                V[dt * 4 + kt * 2 + kl] =
                    *(const bf16x8*)(vp + (size_t)dt * 32 * TOKS + kt * 32 + kl * 16);
}

__device__ __forceinline__ void attn_tile(
    const bf16x8 (&K)[8], const bf16x8 (&V)[8], const bf16x8 (&qf)[4],
    const bf16x8& ones, f32x16& O0, f32x16& O1, f32x16& LA)
{
#pragma unroll
    for (int kt = 0; kt < 2; kt++) {
        f32x16 st0, st1;
#pragma unroll
        for (int j = 0; j < 16; j++) { st0[j] = 0.0f; st1[j] = 0.0f; }
        st0 = MFMA32(K[kt * 4 + 0], qf[0], st0);
        st1 = MFMA32(K[kt * 4 + 1], qf[1], st1);
        st0 = MFMA32(K[kt * 4 + 2], qf[2], st0);
        st1 = MFMA32(K[kt * 4 + 3], qf[3], st1);

        float p[16];
#pragma unroll
        for (int j = 0; j < 16; j++)
            p[j] = __builtin_amdgcn_exp2f(st0[j] + st1[j]);

#pragma unroll
        for (int kl = 0; kl < 2; kl++) {
            const int r0 = kl * 8;
            union { bf16x2 v; unsigned int u; } pa, pb, pc, pd;
            pa.v[0] = (__bf16)p[r0 + 0]; pa.v[1] = (__bf16)p[r0 + 1];
            pb.v[0] = (__bf16)p[r0 + 2]; pb.v[1] = (__bf16)p[r0 + 3];
            pc.v[0] = (__bf16)p[r0 + 4]; pc.v[1] = (__bf16)p[r0 + 5];
            pd.v[0] = (__bf16)p[r0 + 6]; pd.v[1] = (__bf16)p[r0 + 7];
            // key-half exchange with partner lane (lane^32), pure VALU
            asm volatile("v_permlane32_swap_b32 %0, %1"
                         : "+v"(pa.u), "+v"(pc.u));
            asm volatile("v_permlane32_swap_b32 %0, %1"
                         : "+v"(pb.u), "+v"(pd.u));
            union { unsigned int u[4]; bf16x8 v; } af;
            af.u[0] = pa.u; af.u[1] = pb.u; af.u[2] = pc.u; af.u[3] = pd.u;
            __builtin_amdgcn_s_setprio(1);
            LA = MFMA32(af.v, ones, LA);
            O0 = MFMA32(af.v, V[0 + kt * 2 + kl], O0);
            O1 = MFMA32(af.v, V[4 + kt * 2 + kl], O1);
            __builtin_amdgcn_s_setprio(0);
        }
    }
}

__global__ __launch_bounds__(256, 2) void attn_v9_kernel(
    const __bf16* __restrict__ Qh, const __bf16* __restrict__ Kh,
    const __bf16* __restrict__ Vht, __bf16* __restrict__ Y)
{
    const int tid  = threadIdx.x;
    const int w    = tid >> 6;           // 0..3
    const int lane = tid & 63;
    const int l31  = lane & 31;
    const int hi   = lane >> 5;
    const int bh   = blockIdx.x;         // head fastest -> XCD pin
    const int b    = bh >> 4;
    const int h    = bh & 15;
    const int qbase = blockIdx.y * 128 + w * 32;

    const __bf16* Qg = Qh + (size_t)bh * SEQ * HDIM;
    const __bf16* Kg = Kh + (size_t)bh * SEQ * HDIM;
    const __bf16* Vg = Vht + (size_t)(h * HDIM) * TOKS + (size_t)b * SEQ;

    // Q in B-operand layout: lane holds Q[qbase+l31][ks*16 + hi*8 .. +7]
    bf16x8 qf[4];
#pragma unroll
    for (int ks = 0; ks < 4; ks++)
        qf[ks] = *(const bf16x8*)&Qg[(size_t)(qbase + l31) * HDIM + ks * 16 + hi * 8];

    bf16x8 ones;
#pragma unroll
    for (int j = 0; j < 8; j++) ones[j] = (__bf16)1.0f;

    f32x16 O0, O1, LA;
#pragma unroll
    for (int j = 0; j < 16; j++) { O0[j] = 0.0f; O1[j] = 0.0f; LA[j] = 0.0f; }

    // per-lane fragment base pointers
    const __bf16* kLane = Kg + (size_t)l31 * HDIM + hi * 8;
    const __bf16* vLane = Vg + (size_t)l31 * TOKS + hi * 8;

    bf16x8 KA[8], KB[8], VV[8];
    attn_load_k(kLane, KA);                       // tile 0
    const __bf16* kp = kLane + 64 * HDIM;         // K tile t+1
    const __bf16* vp = vLane;                     // V tile t

    for (int i = 0; i < 15; i++) {
        attn_load_v(vp, VV);
        attn_load_k(kp, KB);
        attn_tile(KA, VV, qf, ones, O0, O1, LA);
        vp += 64; kp += 64 * HDIM;
        attn_load_v(vp, VV);
        attn_load_k(kp, KA);
        attn_tile(KB, VV, qf, ones, O0, O1, LA);
        vp += 64; kp += 64 * HDIM;
    }
    // tiles 30, 31
    attn_load_v(vp, VV);
    attn_load_k(kp, KB);
    attn_tile(KA, VV, qf, ones, O0, O1, LA);
    vp += 64;
    attn_load_v(vp, VV);
    attn_tile(KB, VV, qf, ones, O0, O1, LA);

    // LA[reg] = row-sum L for q = qbase + (reg&3)+8*(reg>>2)+4*hi
    __bf16* Yb = Y + (size_t)b * SEQ * CDIM;
#pragma unroll
    for (int reg = 0; reg < 16; reg++) {
        const int qrow  = (reg & 3) + 8 * (reg >> 2) + 4 * hi;
        const float iq  = 1.0f / LA[reg];
        __bf16* yp = Yb + (size_t)(qbase + qrow) * CDIM + h * HDIM + l31;
        yp[0]  = (__bf16)(O0[reg] * iq);
        yp[32] = (__bf16)(O1[reg] * iq);
    }
}

// ---------------------------------------------------------------------------

extern "C" void kernel_launch(void* const* d_in, const int* in_sizes, int n_in,
                              void* d_out, int out_size, void* d_ws, size_t ws_size,
                              hipStream_t stream)
{
    const float* q  = (const float*)d_in[0];
    const float* k  = (const float*)d_in[1];
    const float* v  = (const float*)d_in[2];
    const float* Wq = (const float*)d_in[3];
    const float* bq = (const float*)d_in[4];
    const float* Wk = (const float*)d_in[5];
    const float* bk = (const float*)d_in[6];
    const float* Wv = (const float*)d_in[7];
    const float* bv = (const float*)d_in[8];
    const float* Wo = (const float*)d_in[9];
    const float* bo = (const float*)d_in[10];
    float* out = (float*)d_out;

    const size_t MAT = (size_t)TOKS * CDIM;
    const size_t WN  = (size_t)CDIM * CDIM;

    __bf16* p   = (__bf16*)d_ws;
    __bf16* qb  = p; p += MAT;
    __bf16* kb  = p; p += MAT;
    __bf16* vb  = p; p += MAT;
    __bf16* Wqt = p; p += WN;
    __bf16* Wkt = p; p += WN;
    __bf16* Wvt = p; p += WN;
    __bf16* Wot = p; p += WN;
    __bf16* Qh  = p; p += MAT;   // (B,H,L,D), scaled by QSCALE
    __bf16* Kh  = p; p += MAT;   // (B,H,L,D)
    __bf16* Vht = p; p += MAT;   // [chan][tok], natural order
    __bf16* Yb  = qb;            // alias: qb dead after QKV GEMM

    prep_kernel<<<dim3(7168), dim3(256), 0, stream>>>(
        q, k, v, qb, kb, vb, Wq, Wk, Wv, Wo, Wqt, Wkt, Wvt, Wot);

    qkv_gemm_kernel<<<dim3(8, 32, 3), dim3(512), 0, stream>>>(
        qb, kb, vb, Wqt, Wkt, Wvt, bq, bk, bv, Qh, Kh, Vht);

    attn_v9_kernel<<<dim3(BATCH * NHEAD, SEQ / 128), dim3(256), 0, stream>>>(Qh, Kh, Vht, Yb);

    out_gemm_kernel<<<dim3(16, 32), dim3(512), 0, stream>>>(Yb, Wot, bo, out);
}

// Round 7
// 218.694 us; speedup vs baseline: 1.3112x; 1.3112x over previous
//
#include <hip/hip_runtime.h>
#include <math.h>

#define BATCH 2
#define SEQ   2048
#define CDIM  1024
#define NHEAD 16
#define HDIM  64
#define TOKS  (BATCH * SEQ)   // 4096

typedef __bf16 bf16x8 __attribute__((ext_vector_type(8)));
typedef __bf16 bf16x2 __attribute__((ext_vector_type(2)));
typedef float  f32x4  __attribute__((ext_vector_type(4)));
typedef float  f32x16 __attribute__((ext_vector_type(16)));

#define MFMA16(a, b, c) __builtin_amdgcn_mfma_f32_16x16x32_bf16(a, b, c, 0, 0, 0)
#define MFMA32(a, b, c) __builtin_amdgcn_mfma_f32_32x32x16_bf16(a, b, c, 0, 0, 0)

// 0.125 * log2(e): folded into Q projection so p = exp2(s) == softmax-exact
#define QSCALE 0.1803368801111204f

__device__ __forceinline__ void gload_lds16(const __bf16* g, __bf16* l) {
    __builtin_amdgcn_global_load_lds(
        (const __attribute__((address_space(1))) unsigned int*)g,
        (__attribute__((address_space(3))) unsigned int*)l, 16, 0, 0);
}

// ---------------------------------------------------------------------------
// Prep: blocks [0,6144): fp32->bf16 convert of q,k,v (2048 blocks each).
//       blocks [6144,7168): W (KxN fp32) -> Wt (NxK bf16) transpose, 4 mats.
// ---------------------------------------------------------------------------
__global__ __launch_bounds__(256) void prep_kernel(
    const float* __restrict__ q, const float* __restrict__ k, const float* __restrict__ v,
    __bf16* __restrict__ qo, __bf16* __restrict__ ko, __bf16* __restrict__ vo,
    const float* __restrict__ W0, const float* __restrict__ W1,
    const float* __restrict__ W2, const float* __restrict__ W3,
    __bf16* __restrict__ T0, __bf16* __restrict__ T1,
    __bf16* __restrict__ T2, __bf16* __restrict__ T3)
{
    __shared__ __bf16 Ts[64][72];
    const int bx = blockIdx.x;
    const int tid = threadIdx.x;

    if (bx < 6144) {
        const int t = bx >> 11;
        const size_t i = ((size_t)(bx & 2047) * 256 + tid) * 8;
        const float* s = t == 0 ? q : (t == 1 ? k : v);
        __bf16* d = t == 0 ? qo : (t == 1 ? ko : vo);
        const float4 x = *(const float4*)&s[i];
        const float4 y = *(const float4*)&s[i + 4];
        bf16x8 o;
        o[0] = (__bf16)x.x; o[1] = (__bf16)x.y; o[2] = (__bf16)x.z; o[3] = (__bf16)x.w;
        o[4] = (__bf16)y.x; o[5] = (__bf16)y.y; o[6] = (__bf16)y.z; o[7] = (__bf16)y.w;
        *(bf16x8*)&d[i] = o;
        return;
    }

    const int t  = bx - 6144;
    const int z  = t >> 8;
    const int ry = (t & 255) >> 4;
    const int rx = t & 15;
    const float* W = z == 0 ? W0 : z == 1 ? W1 : z == 2 ? W2 : W3;
    __bf16* T = z == 0 ? T0 : z == 1 ? T1 : z == 2 ? T2 : T3;
    const int rb = ry * 64, cb = rx * 64;
    const int r = tid >> 4;
    const int c4 = (tid & 15) * 4;
#pragma unroll
    for (int p = 0; p < 4; p++) {
        const int rr = p * 16 + r;
        const float4 w4 = *(const float4*)&W[(size_t)(rb + rr) * CDIM + cb + c4];
        Ts[c4 + 0][rr] = (__bf16)w4.x;
        Ts[c4 + 1][rr] = (__bf16)w4.y;
        Ts[c4 + 2][rr] = (__bf16)w4.z;
        Ts[c4 + 3][rr] = (__bf16)w4.w;
    }
    __syncthreads();
    const int n = tid >> 2;
    const int k16 = (tid & 3) * 16;
    *(bf16x8*)&T[(size_t)(cb + n) * CDIM + rb + k16]     = *(const bf16x8*)&Ts[n][k16];
    *(bf16x8*)&T[(size_t)(cb + n) * CDIM + rb + k16 + 8] = *(const bf16x8*)&Ts[n][k16 + 8];
}

// ---------------------------------------------------------------------------
// Fused QKV projection GEMM, one dispatch, z selects:
//   z=0: Qh = (q@Wq + bq)*QSCALE  -> (B,H,L,D) bf16
//   z=1: Kh = (k@Wk + bk)         -> (B,H,L,D) bf16
//   z=2: Vht = (Wv^T @ v^T + bv)  -> [chan][tok] bf16, NATURAL token order
//
// 512 threads / 8 waves on the 128x128 tile; chunked XCD swizzle (96/XCD).
// ---------------------------------------------------------------------------
__global__ __launch_bounds__(512, 6) void qkv_gemm_kernel(
    const __bf16* __restrict__ qb, const __bf16* __restrict__ kb,
    const __bf16* __restrict__ vb,
    const __bf16* __restrict__ Wqt, const __bf16* __restrict__ Wkt,
    const __bf16* __restrict__ Wvt,
    const float* __restrict__ bq, const float* __restrict__ bk,
    const float* __restrict__ bv,
    __bf16* __restrict__ Qh, __bf16* __restrict__ Kh, __bf16* __restrict__ Vht)
{
    __shared__ __bf16 As[128 * 32];
    __shared__ __bf16 Bs[128 * 32];

    const int lin = blockIdx.x + (blockIdx.y << 3) + (blockIdx.z << 8);
    const int nl  = (lin & 7) * 96 + (lin >> 3);
    const int bx  = nl & 7;
    const int by  = (nl >> 3) & 31;
    const int z   = nl >> 8;

    const __bf16* A    = z == 0 ? qb : z == 1 ? kb : Wvt;
    const __bf16* Bt   = z == 0 ? Wqt : z == 1 ? Wkt : vb;
    const float*  bias = z == 0 ? bq : z == 1 ? bk : bv;

    const int tid  = threadIdx.x;
    const int w    = tid >> 6;     // 0..7
    const int lane = tid & 63;
    const int quad = lane >> 4;
    const int c    = lane & 15;
    const int wm   = w >> 1;       // 0..3: 32-row strip
    const int wn   = w & 1;        // 0..1: 64-col strip
    const int rowBase = (z == 2 ? bx : by) * 128;
    const int colBase = (z == 2 ? by : bx) * 128;

    const int sr = lane >> 2;
    const int sk = (lane & 3) * 8;

    f32x4 acc[2][4];
#pragma unroll
    for (int i = 0; i < 2; i++)
#pragma unroll
        for (int j = 0; j < 4; j++) acc[i][j] = (f32x4){0, 0, 0, 0};

    const __bf16* srcA = A  + (size_t)(rowBase + w * 16 + sr) * CDIM + sk;
    const __bf16* srcB = Bt + (size_t)(colBase + w * 16 + sr) * CDIM + sk;
    __bf16* dstA = &As[w * 16 * 32];
    __bf16* dstB = &Bs[w * 16 * 32];

    for (int k0 = 0; k0 < CDIM; k0 += 32) {
        gload_lds16(srcA + k0, dstA);
        gload_lds16(srcB + k0, dstB);
        __syncthreads();

        bf16x8 af[2], bf[4];
#pragma unroll
        for (int i = 0; i < 2; i++)
            af[i] = *(const bf16x8*)&As[(wm * 32 + i * 16 + c) * 32 + quad * 8];
#pragma unroll
        for (int i = 0; i < 4; i++)
            bf[i] = *(const bf16x8*)&Bs[(wn * 64 + i * 16 + c) * 32 + quad * 8];
#pragma unroll
        for (int mi = 0; mi < 2; mi++)
#pragma unroll
            for (int ni = 0; ni < 4; ni++)
                acc[mi][ni] = MFMA16(af[mi], bf[ni], acc[mi][ni]);
        __syncthreads();
    }

#pragma unroll
    for (int mi = 0; mi < 2; mi++) {
#pragma unroll
        for (int ni = 0; ni < 4; ni++) {
            const int col = colBase + wn * 64 + ni * 16 + c;
#pragma unroll
            for (int r = 0; r < 4; r++) {
                const int row = rowBase + wm * 32 + mi * 16 + quad * 4 + r;
                const float val = acc[mi][ni][r];
                if (z == 2) {
                    Vht[(size_t)row * TOKS + col] = (__bf16)(val + bias[row]);
                } else {
                    const int b = row >> 11, l = row & 2047;
                    const int h = col >> 6,  d = col & 63;
                    const float s = (z == 0) ? QSCALE : 1.0f;
                    __bf16* outp = (z == 0) ? Qh : Kh;
                    outp[((((size_t)b * NHEAD + h) * SEQ) + l) * HDIM + d] =
                        (__bf16)((val + bias[col]) * s);
                }
            }
        }
    }
}

// ---------------------------------------------------------------------------
// Final projection GEMM: out(fp32) = Yb(bf16) @ Wot^T + bo.
// 512 threads / 8 waves on the 128x64 tile; chunked XCD swizzle.
// ---------------------------------------------------------------------------
__global__ __launch_bounds__(512, 4) void out_gemm_kernel(
    const __bf16* __restrict__ A, const __bf16* __restrict__ Bt,
    const float* __restrict__ bias, float* __restrict__ out)
{
    __shared__ __bf16 As[128 * 32];
    __shared__ __bf16 Bs[64 * 32];

    const int lin = blockIdx.x + (blockIdx.y << 4);
    const int nl  = (lin & 7) * 64 + (lin >> 3);
    const int bx  = nl & 15;
    const int by  = nl >> 4;

    const int tid  = threadIdx.x;
    const int w    = tid >> 6;
    const int lane = tid & 63;
    const int quad = lane >> 4;
    const int c    = lane & 15;
    const int wm   = w >> 1;
    const int wn   = w & 1;
    const int rowBase = by * 128;
    const int colBase = bx * 64;
    const int sr = lane >> 2;
    const int sk = (lane & 3) * 8;

    f32x4 acc[2][2];
#pragma unroll
    for (int i = 0; i < 2; i++)
#pragma unroll
        for (int j = 0; j < 2; j++) acc[i][j] = (f32x4){0, 0, 0, 0};

    const __bf16* srcA = A + (size_t)(rowBase + w * 16 + sr) * CDIM + sk;
    const __bf16* srcB = Bt + (size_t)(colBase + (w & 3) * 16 + sr) * CDIM + sk;
    __bf16* dstA = &As[w * 16 * 32];
    __bf16* dstB = &Bs[(w & 3) * 16 * 32];

    for (int k0 = 0; k0 < CDIM; k0 += 32) {
        gload_lds16(srcA + k0, dstA);
        if (w < 4) gload_lds16(srcB + k0, dstB);
        __syncthreads();

        bf16x8 af[2], bf[2];
#pragma unroll
        for (int i = 0; i < 2; i++)
            af[i] = *(const bf16x8*)&As[(wm * 32 + i * 16 + c) * 32 + quad * 8];
#pragma unroll
        for (int i = 0; i < 2; i++)
            bf[i] = *(const bf16x8*)&Bs[(wn * 32 + i * 16 + c) * 32 + quad * 8];
#pragma unroll
        for (int mi = 0; mi < 2; mi++)
#pragma unroll
            for (int ni = 0; ni < 2; ni++)
                acc[mi][ni] = MFMA16(af[mi], bf[ni], acc[mi][ni]);
        __syncthreads();
    }

#pragma unroll
    for (int mi = 0; mi < 2; mi++) {
#pragma unroll
        for (int ni = 0; ni < 2; ni++) {
            const int col = colBase + wn * 32 + ni * 16 + c;
#pragma unroll
            for (int r = 0; r < 4; r++) {
                const int row = rowBase + wm * 32 + mi * 16 + quad * 4 + r;
                out[(size_t)row * CDIM + col] = acc[mi][ni][r] + bias[col];
            }
        }
    }
}

// ---------------------------------------------------------------------------
// Attention v10 = v8 compute path (verified) + gload_lds staging.
// 256 thr / 4 waves, 32 q-rows/wave, 32x32x16 MFMA, swapped QK^T,
// in-register softmax (permlane32_swap exchange), L via ones-MFMA.
// Staging: KVBLK=128 keys; K tile [128][64] and V tile [64][128] stored
// LINEAR in LDS via global_load_lds (no ds_writes, no reg round-trip),
// with XOR bank-swizzle applied on the per-lane GLOBAL source address
// (chunk ^= row&7, 16B chunks) and the same XOR on ds_read (rule #21:
// both-sides-or-neither). One barrier per 128-key tile (16 total);
// next tile's 32 gloads issue at tile top -> full-tile compute covers
// L2 latency, so the barrier's implicit vmcnt(0) drain is free.
// LDS 64 KB -> 2 blocks/CU. Grid (B*H, SEQ/128) = 512 blocks.
// ---------------------------------------------------------------------------
__global__ __launch_bounds__(256, 2) void attn_v10_kernel(
    const __bf16* __restrict__ Qh, const __bf16* __restrict__ Kh,
    const __bf16* __restrict__ Vht, __bf16* __restrict__ Y)
{
    __shared__ __align__(16) __bf16 Ks[2][128][64];   // [buf][key][dim] linear
    __shared__ __align__(16) __bf16 Vt[2][64][128];   // [buf][dim][key] linear

    const int tid  = threadIdx.x;
    const int w    = tid >> 6;           // 0..3
    const int lane = tid & 63;
    const int l31  = lane & 31;
    const int hi   = lane >> 5;
    const int swz  = l31 & 7;            // read-side XOR field
    const int bh   = blockIdx.x;         // head fastest -> XCD pin
    const int b    = bh >> 4;
    const int h    = bh & 15;
    const int qbase = blockIdx.y * 128 + w * 32;

    const __bf16* Qg = Qh + (size_t)bh * SEQ * HDIM;
    const __bf16* Kg = Kh + (size_t)bh * SEQ * HDIM;
    const __bf16* Vg = Vht + (size_t)(h * HDIM) * TOKS + (size_t)b * SEQ;

    // Q in B-operand layout: lane holds Q[qbase+l31][ks*16 + hi*8 .. +7]
    bf16x8 qf[4];
#pragma unroll
    for (int ks = 0; ks < 4; ks++)
        qf[ks] = *(const bf16x8*)&Qg[(size_t)(qbase + l31) * HDIM + ks * 16 + hi * 8];

    bf16x8 ones;
#pragma unroll
    for (int j = 0; j < 8; j++) ones[j] = (__bf16)1.0f;

    f32x16 O0, O1, LA;
#pragma unroll
    for (int j = 0; j < 16; j++) { O0[j] = 0.0f; O1[j] = 0.0f; LA[j] = 0.0f; }

    // staging lane decomposition (per gload instr):
    //  K chunk (1 KB = 8 rows x 128B): row8 = lane>>3, kc = lane&7
    //  V chunk (1 KB = 4 rows x 256B): row4 = lane>>4, vc = lane&15
    const int kr8 = lane >> 3, kc = lane & 7;
    const int vr4 = lane >> 4, vc = lane & 15;

    // stage tile starting at token T into buffer bb: 32 chunks / 4 waves
#define STAGE(T, bb)                                                          \
    {                                                                         \
        _Pragma("unroll")                                                     \
        for (int jj = 0; jj < 4; jj++) {                                      \
            const int j = w * 4 + jj;                                         \
            gload_lds16(Kg + (size_t)((T) + 8 * j + kr8) * HDIM               \
                           + ((kc ^ kr8) * 8),                                \
                        &Ks[bb][8 * j][0]);                                   \
            gload_lds16(Vg + (size_t)(4 * j + vr4) * TOKS + (T)               \
                           + ((vc ^ ((4 * j + vr4) & 7)) * 8),                \
                        &Vt[bb][4 * j][0]);                                   \
        }                                                                     \
    }

    STAGE(0, 0);
    __syncthreads();

    int buf = 0;
    for (int t0 = 0; t0 < SEQ; t0 += 128) {
        const int tn = t0 + 128;
        if (tn < SEQ) {
            if (buf == 0) STAGE(tn, 1) else STAGE(tn, 0)
        }

#pragma unroll
        for (int kt = 0; kt < 4; kt++) {
            // S^T subtile: rows = keys kt*32.., cols = q (lane&31)
            f32x16 st0, st1;
#pragma unroll
            for (int j = 0; j < 16; j++) { st0[j] = 0.0f; st1[j] = 0.0f; }
            const bf16x8 kf0 = *(const bf16x8*)&Ks[buf][kt * 32 + l31][((0 + hi) ^ swz) * 8];
            const bf16x8 kf1 = *(const bf16x8*)&Ks[buf][kt * 32 + l31][((2 + hi) ^ swz) * 8];
            const bf16x8 kf2 = *(const bf16x8*)&Ks[buf][kt * 32 + l31][((4 + hi) ^ swz) * 8];
            const bf16x8 kf3 = *(const bf16x8*)&Ks[buf][kt * 32 + l31][((6 + hi) ^ swz) * 8];
            st0 = MFMA32(kf0, qf[0], st0);
            st1 = MFMA32(kf1, qf[1], st1);
            st0 = MFMA32(kf2, qf[2], st0);
            st1 = MFMA32(kf3, qf[3], st1);

            float p[16];
#pragma unroll
            for (int j = 0; j < 16; j++)
                p[j] = __builtin_amdgcn_exp2f(st0[j] + st1[j]);

#pragma unroll
            for (int kl = 0; kl < 2; kl++) {
                const int r0 = kl * 8;
                union { bf16x2 v; unsigned int u; } pa, pb, pc, pd;
                pa.v[0] = (__bf16)p[r0 + 0]; pa.v[1] = (__bf16)p[r0 + 1];
                pb.v[0] = (__bf16)p[r0 + 2]; pb.v[1] = (__bf16)p[r0 + 3];
                pc.v[0] = (__bf16)p[r0 + 4]; pc.v[1] = (__bf16)p[r0 + 5];
                pd.v[0] = (__bf16)p[r0 + 6]; pd.v[1] = (__bf16)p[r0 + 7];
                // key-half exchange with partner lane (lane^32), pure VALU
                asm volatile("v_permlane32_swap_b32 %0, %1"
                             : "+v"(pa.u), "+v"(pc.u));
                asm volatile("v_permlane32_swap_b32 %0, %1"
                             : "+v"(pb.u), "+v"(pd.u));
                union { unsigned int u[4]; bf16x8 v; } af;
                af.u[0] = pa.u; af.u[1] = pb.u; af.u[2] = pc.u; af.u[3] = pd.u;
                // V key-chunk for keys kt*32 + kl*16 + hi*8: cc = kt*4+kl*2+hi
                const int cc = kt * 4 + kl * 2 + hi;
                const bf16x8 vf0 = *(const bf16x8*)&Vt[buf][l31][(cc ^ swz) * 8];
                const bf16x8 vf1 = *(const bf16x8*)&Vt[buf][32 + l31][(cc ^ swz) * 8];
                __builtin_amdgcn_s_setprio(1);
                LA = MFMA32(af.v, ones, LA);
                O0 = MFMA32(af.v, vf0, O0);
                O1 = MFMA32(af.v, vf1, O1);
                __builtin_amdgcn_s_setprio(0);
            }
        }

        __syncthreads();
        buf ^= 1;
    }
#undef STAGE

    // LA[reg] = row-sum L for q = qbase + (reg&3)+8*(reg>>2)+4*hi
    __bf16* Yb = Y + (size_t)b * SEQ * CDIM;
#pragma unroll
    for (int reg = 0; reg < 16; reg++) {
        const int qrow  = (reg & 3) + 8 * (reg >> 2) + 4 * hi;
        const float iq  = 1.0f / LA[reg];
        __bf16* yp = Yb + (size_t)(qbase + qrow) * CDIM + h * HDIM + l31;
        yp[0]  = (__bf16)(O0[reg] * iq);
        yp[32] = (__bf16)(O1[reg] * iq);
    }
}

// ---------------------------------------------------------------------------

extern "C" void kernel_launch(void* const* d_in, const int* in_sizes, int n_in,
                              void* d_out, int out_size, void* d_ws, size_t ws_size,
                              hipStream_t stream)
{
    const float* q  = (const float*)d_in[0];
    const float* k  = (const float*)d_in[1];
    const float* v  = (const float*)d_in[2];
    const float* Wq = (const float*)d_in[3];
    const float* bq = (const float*)d_in[4];
    const float* Wk = (const float*)d_in[5];
    const float* bk = (const float*)d_in[6];
    const float* Wv = (const float*)d_in[7];
    const float* bv = (const float*)d_in[8];
    const float* Wo = (const float*)d_in[9];
    const float* bo = (const float*)d_in[10];
    float* out = (float*)d_out;

    const size_t MAT = (size_t)TOKS * CDIM;
    const size_t WN  = (size_t)CDIM * CDIM;

    __bf16* p   = (__bf16*)d_ws;
    __bf16* qb  = p; p += MAT;
    __bf16* kb  = p; p += MAT;
    __bf16* vb  = p; p += MAT;
    __bf16* Wqt = p; p += WN;
    __bf16* Wkt = p; p += WN;
    __bf16* Wvt = p; p += WN;
    __bf16* Wot = p; p += WN;
    __bf16* Qh  = p; p += MAT;   // (B,H,L,D), scaled by QSCALE
    __bf16* Kh  = p; p += MAT;   // (B,H,L,D)
    __bf16* Vht = p; p += MAT;   // [chan][tok], natural order
    __bf16* Yb  = qb;            // alias: qb dead after QKV GEMM

    prep_kernel<<<dim3(7168), dim3(256), 0, stream>>>(
        q, k, v, qb, kb, vb, Wq, Wk, Wv, Wo, Wqt, Wkt, Wvt, Wot);

    qkv_gemm_kernel<<<dim3(8, 32, 3), dim3(512), 0, stream>>>(
        qb, kb, vb, Wqt, Wkt, Wvt, bq, bk, bv, Qh, Kh, Vht);

    attn_v10_kernel<<<dim3(BATCH * NHEAD, SEQ / 128), dim3(256), 0, stream>>>(Qh, Kh, Vht, Yb);

    out_gemm_kernel<<<dim3(16, 32), dim3(512), 0, stream>>>(Yb, Wot, bo, out);
}

// Round 8
// 217.188 us; speedup vs baseline: 1.3203x; 1.0069x over previous
//
#include <hip/hip_runtime.h>
#include <math.h>

#define BATCH 2
#define SEQ   2048
#define CDIM  1024
#define NHEAD 16
#define HDIM  64
#define TOKS  (BATCH * SEQ)   // 4096

typedef __bf16 bf16x8 __attribute__((ext_vector_type(8)));
typedef __bf16 bf16x2 __attribute__((ext_vector_type(2)));
typedef float  f32x4  __attribute__((ext_vector_type(4)));
typedef float  f32x16 __attribute__((ext_vector_type(16)));

#define MFMA16(a, b, c) __builtin_amdgcn_mfma_f32_16x16x32_bf16(a, b, c, 0, 0, 0)
#define MFMA32(a, b, c) __builtin_amdgcn_mfma_f32_32x32x16_bf16(a, b, c, 0, 0, 0)

// 0.125 * log2(e): folded into Q projection so p = exp2(s) == softmax-exact
#define QSCALE 0.1803368801111204f

__device__ __forceinline__ void gload_lds16(const __bf16* g, __bf16* l) {
    __builtin_amdgcn_global_load_lds(
        (const __attribute__((address_space(1))) unsigned int*)g,
        (__attribute__((address_space(3))) unsigned int*)l, 16, 0, 0);
}

// ---------------------------------------------------------------------------
// Prep: blocks [0,6144): fp32->bf16 convert of q,k,v (2048 blocks each).
//       blocks [6144,7168): W (KxN fp32) -> Wt (NxK bf16) transpose, 4 mats.
// ---------------------------------------------------------------------------
__global__ __launch_bounds__(256) void prep_kernel(
    const float* __restrict__ q, const float* __restrict__ k, const float* __restrict__ v,
    __bf16* __restrict__ qo, __bf16* __restrict__ ko, __bf16* __restrict__ vo,
    const float* __restrict__ W0, const float* __restrict__ W1,
    const float* __restrict__ W2, const float* __restrict__ W3,
    __bf16* __restrict__ T0, __bf16* __restrict__ T1,
    __bf16* __restrict__ T2, __bf16* __restrict__ T3)
{
    __shared__ __bf16 Ts[64][72];
    const int bx = blockIdx.x;
    const int tid = threadIdx.x;

    if (bx < 6144) {
        const int t = bx >> 11;
        const size_t i = ((size_t)(bx & 2047) * 256 + tid) * 8;
        const float* s = t == 0 ? q : (t == 1 ? k : v);
        __bf16* d = t == 0 ? qo : (t == 1 ? ko : vo);
        const float4 x = *(const float4*)&s[i];
        const float4 y = *(const float4*)&s[i + 4];
        bf16x8 o;
        o[0] = (__bf16)x.x; o[1] = (__bf16)x.y; o[2] = (__bf16)x.z; o[3] = (__bf16)x.w;
        o[4] = (__bf16)y.x; o[5] = (__bf16)y.y; o[6] = (__bf16)y.z; o[7] = (__bf16)y.w;
        *(bf16x8*)&d[i] = o;
        return;
    }

    const int t  = bx - 6144;
    const int z  = t >> 8;
    const int ry = (t & 255) >> 4;
    const int rx = t & 15;
    const float* W = z == 0 ? W0 : z == 1 ? W1 : z == 2 ? W2 : W3;
    __bf16* T = z == 0 ? T0 : z == 1 ? T1 : z == 2 ? T2 : T3;
    const int rb = ry * 64, cb = rx * 64;
    const int r = tid >> 4;
    const int c4 = (tid & 15) * 4;
#pragma unroll
    for (int p = 0; p < 4; p++) {
        const int rr = p * 16 + r;
        const float4 w4 = *(const float4*)&W[(size_t)(rb + rr) * CDIM + cb + c4];
        Ts[c4 + 0][rr] = (__bf16)w4.x;
        Ts[c4 + 1][rr] = (__bf16)w4.y;
        Ts[c4 + 2][rr] = (__bf16)w4.z;
        Ts[c4 + 3][rr] = (__bf16)w4.w;
    }
    __syncthreads();
    const int n = tid >> 2;
    const int k16 = (tid & 3) * 16;
    *(bf16x8*)&T[(size_t)(cb + n) * CDIM + rb + k16]     = *(const bf16x8*)&Ts[n][k16];
    *(bf16x8*)&T[(size_t)(cb + n) * CDIM + rb + k16 + 8] = *(const bf16x8*)&Ts[n][k16 + 8];
}

// ---------------------------------------------------------------------------
// Fused QKV projection GEMM, one dispatch, z selects:
//   z=0: Qh = (q@Wq + bq)*QSCALE  -> (B,H,L,D) bf16
//   z=1: Kh = (k@Wk + bk)         -> (B,H,L,D) bf16
//   z=2: Vht = (Wv^T @ v^T + bv)  -> [chan][tok] bf16, NATURAL token order
//
// 512 threads / 8 waves on the 128x128 tile; chunked XCD swizzle (96/XCD).
// ---------------------------------------------------------------------------
__global__ __launch_bounds__(512, 6) void qkv_gemm_kernel(
    const __bf16* __restrict__ qb, const __bf16* __restrict__ kb,
    const __bf16* __restrict__ vb,
    const __bf16* __restrict__ Wqt, const __bf16* __restrict__ Wkt,
    const __bf16* __restrict__ Wvt,
    const float* __restrict__ bq, const float* __restrict__ bk,
    const float* __restrict__ bv,
    __bf16* __restrict__ Qh, __bf16* __restrict__ Kh, __bf16* __restrict__ Vht)
{
    __shared__ __bf16 As[128 * 32];
    __shared__ __bf16 Bs[128 * 32];

    const int lin = blockIdx.x + (blockIdx.y << 3) + (blockIdx.z << 8);
    const int nl  = (lin & 7) * 96 + (lin >> 3);
    const int bx  = nl & 7;
    const int by  = (nl >> 3) & 31;
    const int z   = nl >> 8;

    const __bf16* A    = z == 0 ? qb : z == 1 ? kb : Wvt;
    const __bf16* Bt   = z == 0 ? Wqt : z == 1 ? Wkt : vb;
    const float*  bias = z == 0 ? bq : z == 1 ? bk : bv;

    const int tid  = threadIdx.x;
    const int w    = tid >> 6;     // 0..7
    const int lane = tid & 63;
    const int quad = lane >> 4;
    const int c    = lane & 15;
    const int wm   = w >> 1;       // 0..3: 32-row strip
    const int wn   = w & 1;        // 0..1: 64-col strip
    const int rowBase = (z == 2 ? bx : by) * 128;
    const int colBase = (z == 2 ? by : bx) * 128;

    const int sr = lane >> 2;
    const int sk = (lane & 3) * 8;

    f32x4 acc[2][4];
#pragma unroll
    for (int i = 0; i < 2; i++)
#pragma unroll
        for (int j = 0; j < 4; j++) acc[i][j] = (f32x4){0, 0, 0, 0};

    const __bf16* srcA = A  + (size_t)(rowBase + w * 16 + sr) * CDIM + sk;
    const __bf16* srcB = Bt + (size_t)(colBase + w * 16 + sr) * CDIM + sk;
    __bf16* dstA = &As[w * 16 * 32];
    __bf16* dstB = &Bs[w * 16 * 32];

    for (int k0 = 0; k0 < CDIM; k0 += 32) {
        gload_lds16(srcA + k0, dstA);
        gload_lds16(srcB + k0, dstB);
        __syncthreads();

        bf16x8 af[2], bf[4];
#pragma unroll
        for (int i = 0; i < 2; i++)
            af[i] = *(const bf16x8*)&As[(wm * 32 + i * 16 + c) * 32 + quad * 8];
#pragma unroll
        for (int i = 0; i < 4; i++)
            bf[i] = *(const bf16x8*)&Bs[(wn * 64 + i * 16 + c) * 32 + quad * 8];
#pragma unroll
        for (int mi = 0; mi < 2; mi++)
#pragma unroll
            for (int ni = 0; ni < 4; ni++)
                acc[mi][ni] = MFMA16(af[mi], bf[ni], acc[mi][ni]);
        __syncthreads();
    }

#pragma unroll
    for (int mi = 0; mi < 2; mi++) {
#pragma unroll
        for (int ni = 0; ni < 4; ni++) {
            const int col = colBase + wn * 64 + ni * 16 + c;
#pragma unroll
            for (int r = 0; r < 4; r++) {
                const int row = rowBase + wm * 32 + mi * 16 + quad * 4 + r;
                const float val = acc[mi][ni][r];
                if (z == 2) {
                    Vht[(size_t)row * TOKS + col] = (__bf16)(val + bias[row]);
                } else {
                    const int b = row >> 11, l = row & 2047;
                    const int h = col >> 6,  d = col & 63;
                    const float s = (z == 0) ? QSCALE : 1.0f;
                    __bf16* outp = (z == 0) ? Qh : Kh;
                    outp[((((size_t)b * NHEAD + h) * SEQ) + l) * HDIM + d] =
                        (__bf16)((val + bias[col]) * s);
                }
            }
        }
    }
}

// ---------------------------------------------------------------------------
// Final projection GEMM: out(fp32) = Yb(bf16) @ Wot^T + bo.
// 512 threads / 8 waves on the 128x64 tile; chunked XCD swizzle.
// ---------------------------------------------------------------------------
__global__ __launch_bounds__(512, 4) void out_gemm_kernel(
    const __bf16* __restrict__ A, const __bf16* __restrict__ Bt,
    const float* __restrict__ bias, float* __restrict__ out)
{
    __shared__ __bf16 As[128 * 32];
    __shared__ __bf16 Bs[64 * 32];

    const int lin = blockIdx.x + (blockIdx.y << 4);
    const int nl  = (lin & 7) * 64 + (lin >> 3);
    const int bx  = nl & 15;
    const int by  = nl >> 4;

    const int tid  = threadIdx.x;
    const int w    = tid >> 6;
    const int lane = tid & 63;
    const int quad = lane >> 4;
    const int c    = lane & 15;
    const int wm   = w >> 1;
    const int wn   = w & 1;
    const int rowBase = by * 128;
    const int colBase = bx * 64;
    const int sr = lane >> 2;
    const int sk = (lane & 3) * 8;

    f32x4 acc[2][2];
#pragma unroll
    for (int i = 0; i < 2; i++)
#pragma unroll
        for (int j = 0; j < 2; j++) acc[i][j] = (f32x4){0, 0, 0, 0};

    const __bf16* srcA = A + (size_t)(rowBase + w * 16 + sr) * CDIM + sk;
    const __bf16* srcB = Bt + (size_t)(colBase + (w & 3) * 16 + sr) * CDIM + sk;
    __bf16* dstA = &As[w * 16 * 32];
    __bf16* dstB = &Bs[(w & 3) * 16 * 32];

    for (int k0 = 0; k0 < CDIM; k0 += 32) {
        gload_lds16(srcA + k0, dstA);
        if (w < 4) gload_lds16(srcB + k0, dstB);
        __syncthreads();

        bf16x8 af[2], bf[2];
#pragma unroll
        for (int i = 0; i < 2; i++)
            af[i] = *(const bf16x8*)&As[(wm * 32 + i * 16 + c) * 32 + quad * 8];
#pragma unroll
        for (int i = 0; i < 2; i++)
            bf[i] = *(const bf16x8*)&Bs[(wn * 32 + i * 16 + c) * 32 + quad * 8];
#pragma unroll
        for (int mi = 0; mi < 2; mi++)
#pragma unroll
            for (int ni = 0; ni < 2; ni++)
                acc[mi][ni] = MFMA16(af[mi], bf[ni], acc[mi][ni]);
        __syncthreads();
    }

#pragma unroll
    for (int mi = 0; mi < 2; mi++) {
#pragma unroll
        for (int ni = 0; ni < 2; ni++) {
            const int col = colBase + wn * 32 + ni * 16 + c;
#pragma unroll
            for (int r = 0; r < 4; r++) {
                const int row = rowBase + wm * 32 + mi * 16 + quad * 4 + r;
                out[(size_t)row * CDIM + col] = acc[mi][ni][r] + bias[col];
            }
        }
    }
}

// ---------------------------------------------------------------------------
// Attention v11: split-K across waves. 512 thr / 8 waves; waves 0-3 process
// keys [0,1024), waves 4-7 keys [1024,2048), for the SAME 128 q-rows
// (wave wq=w&3 owns q-rows wq*32..+31 via 32x32x16 MFMA). Doubles total
// waves to 4096 = 16/CU = 4/SIMD (was grid-capped at 2/SIMD) so the serial
// QK->exp2->pack->PV chain of one wave overlaps the MFMA of three others.
// Legal because softmax here is non-rescaled exp2 (log2e folded into Q):
// O = sum p*V and L = sum p are fully associative across key ranges; the
// two halves combine through LDS scratch at the end (zero extra HBM).
// Compute path = verified v8/v10 math; QK MFMAs chained into one
// accumulator (deletes the st0+st1 adds). KVBLK=64 per stream, double-
// buffered, 2 streams: LDS 64 KB -> 2 blocks/CU. gload_lds staging with
// XOR bank-swizzle on the global source + same XOR on ds_read (rule #21).
// Grid (B*H, SEQ/128) = 512 blocks; head fastest -> XCD pin.
// ---------------------------------------------------------------------------
__global__ __launch_bounds__(512, 4) void attn_v11_kernel(
    const __bf16* __restrict__ Qh, const __bf16* __restrict__ Kh,
    const __bf16* __restrict__ Vht, __bf16* __restrict__ Y)
{
    __shared__ __align__(16) __bf16 Ks[2][2][64][64];  // [buf][stream][key][dim]
    __shared__ __align__(16) __bf16 Vt[2][2][64][64];  // [buf][stream][dim][key]

    const int tid  = threadIdx.x;
    const int w    = tid >> 6;           // 0..7
    const int wq   = w & 3;              // q-strip within block
    const int half = w >> 2;             // key-half (0 or 1)
    const int lane = tid & 63;
    const int l31  = lane & 31;
    const int hi   = lane >> 5;
    const int swz  = l31 & 7;            // read-side XOR field
    const int bh   = blockIdx.x;         // head fastest -> XCD pin
    const int b    = bh >> 4;
    const int h    = bh & 15;
    const int qbase = blockIdx.y * 128 + wq * 32;

    const __bf16* Qg = Qh + (size_t)bh * SEQ * HDIM;
    const __bf16* Kg = Kh + (size_t)bh * SEQ * HDIM;
    const __bf16* Vg = Vht + (size_t)(h * HDIM) * TOKS + (size_t)b * SEQ;

    // Q in B-operand layout: lane holds Q[qbase+l31][ks*16 + hi*8 .. +7]
    bf16x8 qf[4];
#pragma unroll
    for (int ks = 0; ks < 4; ks++)
        qf[ks] = *(const bf16x8*)&Qg[(size_t)(qbase + l31) * HDIM + ks * 16 + hi * 8];

    bf16x8 ones;
#pragma unroll
    for (int j = 0; j < 8; j++) ones[j] = (__bf16)1.0f;

    f32x16 O0, O1, LA;
#pragma unroll
    for (int j = 0; j < 16; j++) { O0[j] = 0.0f; O1[j] = 0.0f; LA[j] = 0.0f; }

    // staging decomposition: 32 one-KB chunks per tile-step over 8 waves.
    // chunk cch = w*4+jj: cch<16 -> K (stream (cch>>3)&1, sub j=cch&7);
    //                     else   -> V (same fields). Each chunk = 8 rows
    // of 128 B; lane: kr8 = row-in-chunk, kc = 16B slot; source slot is
    // XOR-swizzled by row&7 (= kr8), LDS dest linear.
    const int kr8 = lane >> 3, kc = lane & 7;

#define STAGE(T, bb)                                                          \
    {                                                                         \
        _Pragma("unroll")                                                     \
        for (int jj = 0; jj < 4; jj++) {                                      \
            const int cch = w * 4 + jj;                                       \
            const int s  = (cch >> 3) & 1;                                    \
            const int j  = cch & 7;                                           \
            if (cch < 16)                                                     \
                gload_lds16(Kg + (size_t)(s * 1024 + (T) + 8 * j + kr8) * HDIM \
                               + ((kc ^ kr8) * 8),                            \
                            &Ks[bb][s][8 * j][0]);                            \
            else                                                              \
                gload_lds16(Vg + (size_t)(8 * j + kr8) * TOKS                 \
                               + s * 1024 + (T) + ((kc ^ kr8) * 8),           \
                            &Vt[bb][s][8 * j][0]);                            \
        }                                                                     \
    }

    STAGE(0, 0);
    __syncthreads();

    int buf = 0;
    for (int t0 = 0; t0 < 1024; t0 += 64) {
        const int tn = t0 + 64;
        if (tn < 1024) {
            if (buf == 0) STAGE(tn, 1) else STAGE(tn, 0)
        }

#pragma unroll
        for (int kt = 0; kt < 2; kt++) {
            // S^T subtile: rows = keys half*1024 + t0 + kt*32.., cols = q
            f32x16 st;
#pragma unroll
            for (int j = 0; j < 16; j++) st[j] = 0.0f;
            const bf16x8 kf0 = *(const bf16x8*)&Ks[buf][half][kt * 32 + l31][((0 + hi) ^ swz) * 8];
            const bf16x8 kf1 = *(const bf16x8*)&Ks[buf][half][kt * 32 + l31][((2 + hi) ^ swz) * 8];
            const bf16x8 kf2 = *(const bf16x8*)&Ks[buf][half][kt * 32 + l31][((4 + hi) ^ swz) * 8];
            const bf16x8 kf3 = *(const bf16x8*)&Ks[buf][half][kt * 32 + l31][((6 + hi) ^ swz) * 8];
            st = MFMA32(kf0, qf[0], st);
            st = MFMA32(kf1, qf[1], st);
            st = MFMA32(kf2, qf[2], st);
            st = MFMA32(kf3, qf[3], st);

            float p[16];
#pragma unroll
            for (int j = 0; j < 16; j++)
                p[j] = __builtin_amdgcn_exp2f(st[j]);

#pragma unroll
            for (int kl = 0; kl < 2; kl++) {
                const int r0 = kl * 8;
                union { bf16x2 v; unsigned int u; } pa, pb, pc, pd;
                pa.v[0] = (__bf16)p[r0 + 0]; pa.v[1] = (__bf16)p[r0 + 1];
                pb.v[0] = (__bf16)p[r0 + 2]; pb.v[1] = (__bf16)p[r0 + 3];
                pc.v[0] = (__bf16)p[r0 + 4]; pc.v[1] = (__bf16)p[r0 + 5];
                pd.v[0] = (__bf16)p[r0 + 6]; pd.v[1] = (__bf16)p[r0 + 7];
                // key-half exchange with partner lane (lane^32), pure VALU
                asm volatile("v_permlane32_swap_b32 %0, %1"
                             : "+v"(pa.u), "+v"(pc.u));
                asm volatile("v_permlane32_swap_b32 %0, %1"
                             : "+v"(pb.u), "+v"(pd.u));
                union { unsigned int u[4]; bf16x8 v; } af;
                af.u[0] = pa.u; af.u[1] = pb.u; af.u[2] = pc.u; af.u[3] = pd.u;
                // V key-chunk for keys kt*32 + kl*16 + hi*8: cc = kt*4+kl*2+hi
                const int cc = kt * 4 + kl * 2 + hi;
                const bf16x8 vf0 = *(const bf16x8*)&Vt[buf][half][l31][(cc ^ swz) * 8];
                const bf16x8 vf1 = *(const bf16x8*)&Vt[buf][half][32 + l31][(cc ^ swz) * 8];
                __builtin_amdgcn_s_setprio(1);
                LA = MFMA32(af.v, ones, LA);
                O0 = MFMA32(af.v, vf0, O0);
                O1 = MFMA32(af.v, vf1, O1);
                __builtin_amdgcn_s_setprio(0);
            }
        }

        __syncthreads();
        buf ^= 1;
    }
#undef STAGE

    // combine the two key-halves through LDS scratch (tile buffers are dead;
    // the loop's trailing barrier guarantees all compute is done)
    float* scr  = (float*)&Ks[0][0][0][0];   // 32 KB: O0 (16 KB) + O1 (16 KB)
    float* scr2 = (float*)&Vt[0][0][0][0];   // 16 KB: LA
    if (half == 1) {
        *(f32x16*)&scr [(wq * 64 + lane) * 16]        = O0;
        *(f32x16*)&scr [4096 + (wq * 64 + lane) * 16] = O1;
        *(f32x16*)&scr2[(wq * 64 + lane) * 16]        = LA;
    }
    __syncthreads();
    if (half == 0) {
        O0 += *(const f32x16*)&scr [(wq * 64 + lane) * 16];
        O1 += *(const f32x16*)&scr [4096 + (wq * 64 + lane) * 16];
        LA += *(const f32x16*)&scr2[(wq * 64 + lane) * 16];

        // LA[reg] = row-sum L for q = qbase + (reg&3)+8*(reg>>2)+4*hi
        __bf16* Yb = Y + (size_t)b * SEQ * CDIM;
#pragma unroll
        for (int reg = 0; reg < 16; reg++) {
            const int qrow  = (reg & 3) + 8 * (reg >> 2) + 4 * hi;
            const float iq  = 1.0f / LA[reg];
            __bf16* yp = Yb + (size_t)(qbase + qrow) * CDIM + h * HDIM + l31;
            yp[0]  = (__bf16)(O0[reg] * iq);
            yp[32] = (__bf16)(O1[reg] * iq);
        }
    }
}

// ---------------------------------------------------------------------------

extern "C" void kernel_launch(void* const* d_in, const int* in_sizes, int n_in,
                              void* d_out, int out_size, void* d_ws, size_t ws_size,
                              hipStream_t stream)
{
    const float* q  = (const float*)d_in[0];
    const float* k  = (const float*)d_in[1];
    const float* v  = (const float*)d_in[2];
    const float* Wq = (const float*)d_in[3];
    const float* bq = (const float*)d_in[4];
    const float* Wk = (const float*)d_in[5];
    const float* bk = (const float*)d_in[6];
    const float* Wv = (const float*)d_in[7];
    const float* bv = (const float*)d_in[8];
    const float* Wo = (const float*)d_in[9];
    const float* bo = (const float*)d_in[10];
    float* out = (float*)d_out;

    const size_t MAT = (size_t)TOKS * CDIM;
    const size_t WN  = (size_t)CDIM * CDIM;

    __bf16* p   = (__bf16*)d_ws;
    __bf16* qb  = p; p += MAT;
    __bf16* kb  = p; p += MAT;
    __bf16* vb  = p; p += MAT;
    __bf16* Wqt = p; p += WN;
    __bf16* Wkt = p; p += WN;
    __bf16* Wvt = p; p += WN;
    __bf16* Wot = p; p += WN;
    __bf16* Qh  = p; p += MAT;   // (B,H,L,D), scaled by QSCALE
    __bf16* Kh  = p; p += MAT;   // (B,H,L,D)
    __bf16* Vht = p; p += MAT;   // [chan][tok], natural order
    __bf16* Yb  = qb;            // alias: qb dead after QKV GEMM

    prep_kernel<<<dim3(7168), dim3(256), 0, stream>>>(
        q, k, v, qb, kb, vb, Wq, Wk, Wv, Wo, Wqt, Wkt, Wvt, Wot);

    qkv_gemm_kernel<<<dim3(8, 32, 3), dim3(512), 0, stream>>>(
        qb, kb, vb, Wqt, Wkt, Wvt, bq, bk, bv, Qh, Kh, Vht);

    attn_v11_kernel<<<dim3(BATCH * NHEAD, SEQ / 128), dim3(512), 0, stream>>>(Qh, Kh, Vht, Yb);

    out_gemm_kernel<<<dim3(16, 32), dim3(512), 0, stream>>>(Yb, Wot, bo, out);
}